// Round 7
// baseline (8405.688 us; speedup 1.0000x reference)
//
#include <hip/hip_runtime.h>
#include <cstdint>
#include <cstddef>

// Problem constants (fixed by the reference)
#define NB 32      // batch
#define NT 1024    // timesteps
#define ND 512     // input dim (== hidden)
#define NH 512     // hidden
#define NG 2048    // 4*H gate width
#define SEQELEMS ((size_t)NB * NT * NH)   // 16,777,216
#define RING 4     // h time-ring depth (skew bound < 3, see proof in comments)

#define SYS __HIP_MEMORY_SCOPE_SYSTEM
#define ESC_MISS 4096   // local-poll misses before sticky escalation (~0.45ms once)

typedef __attribute__((ext_vector_type(8))) short bf16x8;
typedef __attribute__((ext_vector_type(4))) float f32x4;

__device__ __forceinline__ unsigned short f2bf(float f) {
    union { float f; unsigned u; } v; v.f = f;
    unsigned r = v.u + 0x7fffu + ((v.u >> 16) & 1u);   // RNE
    return (unsigned short)(r >> 16);
}
__device__ __forceinline__ float sigf(float x)  { return 1.f / (1.f + __expf(-x)); }
__device__ __forceinline__ float tanhf_(float x){ return 1.f - 2.f / (1.f + __expf(2.f * x)); }

// ---- XCD-local (L2-coherent) primitives: sc0 = bypass L1, serve from L2 ----
__device__ __forceinline__ int ld_flag_sc0(const int* p) {
    int v;
    asm volatile("global_load_dword %0, %1, off sc0\n\ts_waitcnt vmcnt(0)"
                 : "=v"(v) : "v"(p) : "memory");
    return v;
}
// 8x16B fragment load, L2 path. p0/p1 are bases for rows ln and ln+16;
// a{0,1}v[ks] = 16B at base + ks*64B. One waitcnt for all 8.
// NOTE gfx950 modifier grammar: offset: immediate BEFORE cache bits.
__device__ __forceinline__ void ld8_sc0(bf16x8 a0v[4], bf16x8 a1v[4],
                                        const unsigned short* p0,
                                        const unsigned short* p1) {
    asm volatile(
        "global_load_dwordx4 %0, %8, off sc0\n\t"
        "global_load_dwordx4 %1, %8, off offset:64 sc0\n\t"
        "global_load_dwordx4 %2, %8, off offset:128 sc0\n\t"
        "global_load_dwordx4 %3, %8, off offset:192 sc0\n\t"
        "global_load_dwordx4 %4, %9, off sc0\n\t"
        "global_load_dwordx4 %5, %9, off offset:64 sc0\n\t"
        "global_load_dwordx4 %6, %9, off offset:128 sc0\n\t"
        "global_load_dwordx4 %7, %9, off offset:192 sc0\n\t"
        "s_waitcnt vmcnt(0)"
        : "=&v"(a0v[0]), "=&v"(a0v[1]), "=&v"(a0v[2]), "=&v"(a0v[3]),
          "=&v"(a1v[0]), "=&v"(a1v[1]), "=&v"(a1v[2]), "=&v"(a1v[3])
        : "v"(p0), "v"(p1) : "memory");
}
// same, system path (sc0 sc1) — proven v8 semantics
__device__ __forceinline__ void ld8_sys(bf16x8 a0v[4], bf16x8 a1v[4],
                                        const unsigned short* p0,
                                        const unsigned short* p1) {
    asm volatile(
        "global_load_dwordx4 %0, %8, off sc0 sc1\n\t"
        "global_load_dwordx4 %1, %8, off offset:64 sc0 sc1\n\t"
        "global_load_dwordx4 %2, %8, off offset:128 sc0 sc1\n\t"
        "global_load_dwordx4 %3, %8, off offset:192 sc0 sc1\n\t"
        "global_load_dwordx4 %4, %9, off sc0 sc1\n\t"
        "global_load_dwordx4 %5, %9, off offset:64 sc0 sc1\n\t"
        "global_load_dwordx4 %6, %9, off offset:128 sc0 sc1\n\t"
        "global_load_dwordx4 %7, %9, off offset:192 sc0 sc1\n\t"
        "s_waitcnt vmcnt(0)"
        : "=&v"(a0v[0]), "=&v"(a0v[1]), "=&v"(a0v[2]), "=&v"(a0v[3]),
          "=&v"(a1v[0]), "=&v"(a1v[1]), "=&v"(a1v[2]), "=&v"(a1v[3])
        : "v"(p0), "v"(p1) : "memory");
}

// ---------------- prologue: fp32 -> bf16 convert of x ----------------
__global__ void cvt_bf16_kernel(const float* __restrict__ src,
                                unsigned short* __restrict__ dst, int n4) {
    int i = blockIdx.x * blockDim.x + threadIdx.x;
    if (i < n4) {
        float4 v = ((const float4*)src)[i];
        ushort4 o;
        o.x = f2bf(v.x); o.y = f2bf(v.y); o.z = f2bf(v.z); o.w = f2bf(v.w);
        ((ushort4*)dst)[i] = o;
    }
}

// ---------------- main self-timed LSTM kernel (v12 = v11 + asm fix) ----------------
// TOPOLOGY CHANGE: 32 blocks x 16 hidden cols per layer, one layer per XCD
// (blockIdx%8 == XCD round-robin; residues >=2 exit). Intra-layer h handshake
// goes through the XCD-LOCAL L2 (sc0 stores/loads, ~200cy hops) into a 4-slot
// time ring; flags are strict (vmcnt(0) drain before flag — null-cost per v8).
// Skew proof for RING=4: slot (t-1)%4 is only rewritten at phase B of t+3,
// which requires all blocks past phase A of t+2; all reads of that slot
// happen in phase A of t — long done. Cross-layer (XCD0->XCD1) keeps the
// PROVEN system-scope path with slack: layer-1 amortizes its y-flag poll
// 8 steps at a time.
// SAFETY: if blockIdx%8 != XCD on this part, local flags never advance ->
// sticky per-wave escalation to global mirror (system flags + ys_global),
// i.e. v8 behavior: slow-but-correct, no hang, no silent staleness (ring is
// only read under its own strict local flag).
__launch_bounds__(512, 2)
__global__ void lstm_v12(const unsigned short* __restrict__ xb,   // [B][T][512] bf16
                         unsigned short* __restrict__ ysg,        // [2][T][B][512] bf16 global mirror
                         unsigned short* __restrict__ ring,       // [2][RING][B][512] bf16 local
                         int* __restrict__ flagsL,                // [2][32][8] local (sc0)
                         int* __restrict__ flagsG,                // [2][32][8] global (system)
                         const float* __restrict__ Wx,            // [2][512][2048]
                         const float* __restrict__ bx,            // [2][2048]
                         const float* __restrict__ Wh,            // [2][512][2048]
                         const float* __restrict__ bh,            // [2][2048]
                         float* __restrict__ out)                 // seq | h | c
{
    // part[2][8][32][68] f32 (double-buffered by t-parity) = 139,264 B;
    // weight-staging buffer (33,024 B) overlays it (dead after prologue).
    __shared__ __align__(16) unsigned char smem[139264];
    float (*part)[8][32][68] = reinterpret_cast<float (*)[8][32][68]>(smem);
    unsigned short (*Wst)[1032] = reinterpret_cast<unsigned short (*)[1032]>(smem);

    const int bid   = blockIdx.x;
    const int layer = bid & 7;          // residue == XCD (round-robin model)
    if (layer >= 2) return;             // 6 idle XCDs; we're latency-bound
    const int grp = bid >> 3;           // 0..31 hidden-column group
    const int j0  = grp * 16;

    const int tid  = threadIdx.x;
    const int wid  = tid >> 6;          // 8 waves: 0-3 x/y K-slices, 4-7 h K-slices
    const int lane = tid & 63;
    const int q    = lane >> 4;
    const int ln   = lane & 15;
    const bool hwave = (wid >= 4);

    // ---- stage weights (64 gate cols x 1024 K) -> VGPRs, 4 passes ----
    bf16x8 breg[4][4];                  // [ks][gate]
    for (int p = 0; p < 4; ++p) {
        for (int idx = tid; idx < 16 * 1024; idx += 512) {
            int jj = idx >> 10, k = idx & 1023;
            int col = p * 512 + j0 + jj;
            float w = (k < 512)
                ? Wx[(size_t)layer * 512 * NG + (size_t)k * NG + col]
                : Wh[(size_t)layer * 512 * NG + (size_t)(k - 512) * NG + col];
            Wst[jj][k] = f2bf(w);
        }
        __syncthreads();
        #pragma unroll
        for (int ks = 0; ks < 4; ++ks)
            breg[ks][p] = *(const bf16x8*)&Wst[ln][wid * 128 + ks * 32 + q * 8];
        __syncthreads();
    }

    // ---- per-thread constants: phase-B identity (pm,pj), bias, cell state ----
    const int pm = tid >> 4, pj = tid & 15;    // 32 rows x 16 cols, all 512 threads
    float bias_[4];
    #pragma unroll
    for (int gg = 0; gg < 4; ++gg) {
        int col = gg * 512 + j0 + pj;
        bias_[gg] = bx[layer * NG + col] + bh[layer * NG + col];
    }
    float creg = 0.f;

    const unsigned short* y0g   = ysg;                              // layer-0 global y
    unsigned short*       myg   = ysg + (size_t)layer * SEQELEMS;   // own global mirror
    unsigned short*       myring= ring + (size_t)layer * RING * 32 * 512;
    int* flL = flagsL + layer * 256;
    int* flG = flagsG + layer * 256;

    // poll lane mappings: 8 producer groups x 8 phase-B waves = 64 flags/wave
    const int hfidx = (8 * (wid - 4) + (lane >> 3)) * 8 + (lane & 7);  // valid if hwave
    const int yfidx = (8 * wid + (lane >> 3)) * 8 + (lane & 7);        // valid if wid<4

    bool esc = false;       // sticky: local path failed -> global forever
    int ycleared = -1;      // layer-1 y-flag amortization watermark

    for (int t = 0; t < NT; ++t) {
        // ---- phase A: dependency wait + A-fragment loads ----
        bf16x8 a0v[4], a1v[4];
        if (!hwave) {
            if (layer == 0) {
                // static x input, plain cached loads (slab shared by all 32
                // blocks on this XCD -> L2 reuse)
                #pragma unroll
                for (int ks = 0; ks < 4; ++ks) {
                    const int klane = wid * 128 + ks * 32 + q * 8;
                    const size_t base = ((size_t)ln * NT + t) * 512 + klane;
                    a0v[ks] = *(const bf16x8*)(xb + base);
                    a1v[ks] = *(const bf16x8*)(xb + base + (size_t)16 * NT * 512);
                }
            } else {
                // y(t) from layer 0: system path with slack (amortized 8-step poll)
                if (ycleared < t) {
                    int tt = t + 7; if (tt > NT - 1) tt = NT - 1;
                    const int* fp = flagsG + yfidx;   // layer-0 global flags
                    for (;;) {
                        int v = __hip_atomic_load(fp, __ATOMIC_RELAXED, SYS);
                        if (__ballot(v >= tt) == ~0ull) break;
                        __builtin_amdgcn_s_sleep(1);
                    }
                    ycleared = tt;
                    asm volatile("" ::: "memory");
                }
                const unsigned short* p0 =
                    y0g + ((size_t)t * 32 + ln) * 512 + wid * 128 + q * 8;
                ld8_sys(a0v, a1v, p0, p0 + 16 * 512);
            }
        } else if (t > 0) {
            const int tw = t - 1;
            // strict flag wait: local L2 path, sticky-escalate to global
            if (!esc) {
                int miss = 0;
                for (;;) {
                    int v = ld_flag_sc0(flL + hfidx);
                    if (__ballot(v >= tw) == ~0ull) break;
                    if (++miss > ESC_MISS) { esc = true; break; }
                    __builtin_amdgcn_s_sleep(1);
                }
            }
            if (esc) {
                for (;;) {
                    int v = __hip_atomic_load(flG + hfidx, __ATOMIC_RELAXED, SYS);
                    if (__ballot(v >= tw) == ~0ull) break;
                    __builtin_amdgcn_s_sleep(1);
                }
            }
            asm volatile("" ::: "memory");
            const int kloc = (wid - 4) * 128 + q * 8;
            if (!esc) {
                const unsigned short* p0 =
                    myring + (((size_t)(tw & (RING - 1))) * 32 + ln) * 512 + kloc;
                ld8_sc0(a0v, a1v, p0, p0 + 16 * 512);
            } else {
                const unsigned short* p0 =
                    myg + ((size_t)tw * 32 + ln) * 512 + kloc;
                ld8_sys(a0v, a1v, p0, p0 + 16 * 512);
            }
        } else {
            const bf16x8 z = {0, 0, 0, 0, 0, 0, 0, 0};
            #pragma unroll
            for (int ks = 0; ks < 4; ++ks) { a0v[ks] = z; a1v[ks] = z; }
        }

        // ---- MFMA: 2 M-tiles x 4 gate-tiles x 4 K-slices = 32 ----
        f32x4 acc0[4] = {{0,0,0,0},{0,0,0,0},{0,0,0,0},{0,0,0,0}};
        f32x4 acc1[4] = {{0,0,0,0},{0,0,0,0},{0,0,0,0},{0,0,0,0}};
        #pragma unroll
        for (int ks = 0; ks < 4; ++ks) {
            #pragma unroll
            for (int gg = 0; gg < 4; ++gg) {
                acc0[gg] = __builtin_amdgcn_mfma_f32_16x16x32_bf16(a0v[ks], breg[ks][gg], acc0[gg], 0,0,0);
                acc1[gg] = __builtin_amdgcn_mfma_f32_16x16x32_bf16(a1v[ks], breg[ks][gg], acc1[gg], 0,0,0);
            }
        }
        float (*pp)[32][68] = part[t & 1];
        #pragma unroll
        for (int gg = 0; gg < 4; ++gg) {
            #pragma unroll
            for (int r = 0; r < 4; ++r) {   // C/D: col=lane&15, row=quad*4+r (m89)
                pp[wid][     q*4 + r][gg*16 + ln] = acc0[gg][r];
                pp[wid][16 + q*4 + r][gg*16 + ln] = acc1[gg][r];
            }
        }
        __syncthreads();   // S1 (only barrier; part[] double-buffered by parity)

        // ---- phase B: reduce + gates + state + publish (all 512 threads) ----
        {
            float gv[4];
            #pragma unroll
            for (int gg = 0; gg < 4; ++gg) {
                float v = bias_[gg];
                #pragma unroll
                for (int k8 = 0; k8 < 8; ++k8) v += pp[k8][pm][gg*16 + pj];
                gv[gg] = v;
            }
            float f  = sigf(gv[0]);
            float gt = tanhf_(gv[1]);
            float i  = sigf(gv[2]);
            float o  = sigf(gv[3]);
            creg = f * creg + i * gt;
            float h = o * tanhf_(creg);

            // pack 4 adjacent cols into one 8B store (threads pj%4==0)
            int hv = (int)f2bf(h);
            int h1 = __shfl_down(hv, 1);
            int h2 = __shfl_down(hv, 2);
            int h3 = __shfl_down(hv, 3);
            if ((pj & 3) == 0) {
                unsigned long long qv =
                      (unsigned long long)(unsigned short)hv
                    | ((unsigned long long)(unsigned short)h1 << 16)
                    | ((unsigned long long)(unsigned short)h2 << 32)
                    | ((unsigned long long)(unsigned short)h3 << 48);
                // global mirror (system, proven): feeds layer-1 + escalation
                const size_t go = ((size_t)t * 32 + pm) * 512 + j0 + pj;
                __hip_atomic_store((unsigned long long*)(myg + go), qv,
                                   __ATOMIC_RELAXED, SYS);
                // local ring (sc0 -> XCD L2): the fast intra-layer path
                const size_t ro = (((size_t)(t & (RING - 1))) * 32 + pm) * 512 + j0 + pj;
                asm volatile("global_store_dwordx2 %0, %1, off sc0"
                             :: "v"(myring + ro), "v"(qv) : "memory");
            }
            // STRICT flags: drain data stores first (ring reuse means poison
            // checks can't protect; drain was proven null-cost in v8)
            asm volatile("s_waitcnt vmcnt(0)" ::: "memory");
            if (lane == 0) {
                const int fi = grp * 8 + wid;   // this wave owns rows [4*wid,4*wid+4)
                asm volatile("global_store_dword %0, %1, off sc0"
                             :: "v"(flL + fi), "v"(t) : "memory");
                __hip_atomic_store(flG + fi, t, __ATOMIC_RELAXED, SYS);
            }

            // off-critical-path outputs
            if (layer == 1) out[((size_t)pm * NT + t) * 512 + j0 + pj] = h;
            if (t == NT - 1) {
                const size_t hoff = SEQELEMS + ((size_t)pm * 2 + layer) * 512 + j0 + pj;
                out[hoff] = h;
                out[hoff + (size_t)NB * 2 * 512] = creg;
            }
        }
        // no trailing barrier: next part writes go to the other parity buffer,
        // and nobody passes the next S1 until all finish this phase B
    }
}

extern "C" void kernel_launch(void* const* d_in, const int* in_sizes, int n_in,
                              void* d_out, int out_size, void* d_ws, size_t ws_size,
                              hipStream_t stream) {
    const float* x  = (const float*)d_in[0];
    const float* Wx = (const float*)d_in[1];
    const float* bx = (const float*)d_in[2];
    const float* Wh = (const float*)d_in[3];
    const float* bh = (const float*)d_in[4];
    float* out = (float*)d_out;

    // ws: x_bf16 | ys_global [2][T][B][512] | ring [2][RING][B][512] |
    //     flagsL [512] | flagsG [512]   (~96.3 MB)
    // harness poisons ws with 0xAA: flags read negative = not ready
    unsigned short* xb   = (unsigned short*)d_ws;
    unsigned short* ysg  = xb + SEQELEMS;
    unsigned short* ring = ysg + 2 * SEQELEMS;
    int* flagsL = (int*)(ring + (size_t)2 * RING * 32 * 512);
    int* flagsG = flagsL + 512;

    int n4 = (int)(SEQELEMS / 4);
    cvt_bf16_kernel<<<dim3((n4 + 255) / 256), dim3(256), 0, stream>>>(x, xb, n4);

    void* args[] = { (void*)&xb, (void*)&ysg, (void*)&ring, (void*)&flagsL,
                     (void*)&flagsG, (void*)&Wx, (void*)&bx, (void*)&Wh,
                     (void*)&bh, (void*)&out };
    hipLaunchCooperativeKernel((void*)lstm_v12, dim3(256), dim3(512), args, 0, stream);
}